// Round 6
// baseline (541.418 us; speedup 1.0000x reference)
//
#include <hip/hip_runtime.h>

// MHA forward. f32 in/out; bf16 MFMA compute (16x16x32), fp32 accum.
// Pipeline: cvt_x + transposeW -> merged QKV GEMM -> flash attention
//           (64-row q-tiles, Q in regs, reg-prefetch K/V pipeline) -> out GEMM.
// Workspace (u16): WqT,WkT,WvT (contig, = 3072x1024 Bt), WoT, xb/Ctx (alias),
// Q, K, Vt = 72 MB.
//
// R6 vs R5: (1) attn back to 64-row tiles (2048 blocks) + register-prefetch
// K/V staging (loads issued one compute-phase ahead), LDS 25.5KB, 6 blk/CU.
// (2) QKV GEMMs merged into one kernel (seg-switched epilogue).

typedef unsigned short u16;
typedef __attribute__((ext_vector_type(8))) short short8;   // 8 bf16
typedef __attribute__((ext_vector_type(4))) float floatx4;  // 4 fp32

#define NEG_BIG (-1e30f)

__device__ __forceinline__ u16 f2bf(float f) {
  unsigned int u = __builtin_bit_cast(unsigned int, f);
  u += 0x7fffu + ((u >> 16) & 1u);
  return (u16)(u >> 16);
}

__device__ __forceinline__ short8 cvt8(const float* __restrict__ p) {
  const floatx4 a = *(const floatx4*)p;
  const floatx4 b = *(const floatx4*)(p + 4);
  short8 r;
  r[0] = (short)f2bf(a[0]); r[1] = (short)f2bf(a[1]);
  r[2] = (short)f2bf(a[2]); r[3] = (short)f2bf(a[3]);
  r[4] = (short)f2bf(b[0]); r[5] = (short)f2bf(b[1]);
  r[6] = (short)f2bf(b[2]); r[7] = (short)f2bf(b[3]);
  return r;
}

// async global->LDS, 16B/lane; LDS dest = wave-uniform base + lane*16 [m97]
__device__ __forceinline__ void gll16(const u16* g, u16* l) {
  __builtin_amdgcn_global_load_lds((const __attribute__((address_space(1))) void*)g,
                                   (__attribute__((address_space(3))) void*)l,
                                   16, 0, 0);
}

// ---------------------------------------------------------------------------
__global__ void cvt_x(const float* __restrict__ x, u16* __restrict__ xb) {
  const int i = blockIdx.x * 256 + threadIdx.x;  // 8 elems each
  *(short8*)(xb + (size_t)i * 8) = cvt8(x + (size_t)i * 8);
}

// ---------------------------------------------------------------------------
// 1024x1024 transpose + f32->bf16 (x4 matrices via grid.z).
__global__ void transpose4(const float* __restrict__ s0, const float* __restrict__ s1,
                           const float* __restrict__ s2, const float* __restrict__ s3,
                           u16* __restrict__ d0, u16* __restrict__ d1,
                           u16* __restrict__ d2, u16* __restrict__ d3) {
  __shared__ u16 tile[64][72];
  const float* src; u16* dst;
  switch (blockIdx.z) {
    case 0: src = s0; dst = d0; break;
    case 1: src = s1; dst = d1; break;
    case 2: src = s2; dst = d2; break;
    default: src = s3; dst = d3; break;
  }
  const int t = threadIdx.x;
  const int c = t & 63, rg = t >> 6;
  const int x0 = blockIdx.x * 64, y0 = blockIdx.y * 64;
#pragma unroll
  for (int i = 0; i < 16; ++i) {
    const int row = rg * 16 + i;
    tile[row][c] = f2bf(src[(size_t)(y0 + row) * 1024 + x0 + c]);
  }
  __syncthreads();
#pragma unroll
  for (int i = 0; i < 16; ++i) {
    const int row = rg * 16 + i;
    dst[(size_t)(x0 + row) * 1024 + y0 + c] = tile[c][row];
  }
}

// ---------------------------------------------------------------------------
// Merged QKV GEMM: A[8192,1024] bf16 @ Bt[3072,1024]^T (WqT|WkT|WvT) + bias.
// 128x128 tile, BK=32, m97 gll staging. Epilogue routes by segment:
// seg0 -> Qb [b,h,l,dh], seg1 -> Kb [b,h,l,dh], seg2 -> Vtb [b,h,dh,l].
__global__ __launch_bounds__(256, 2) void gemm_qkv(
    const u16* __restrict__ A, const u16* __restrict__ Bt,
    const float* __restrict__ bq, const float* __restrict__ bk,
    const float* __restrict__ bv,
    u16* __restrict__ Qb, u16* __restrict__ Kb, u16* __restrict__ Vtb) {
  const int K = 1024;
  __shared__ __align__(16) u16 As[128 * 32];
  __shared__ __align__(16) u16 Bs[128 * 32];
  const int t = threadIdx.x;
  const int w = t >> 6, l = t & 63;
  const int quad = l >> 4, l16 = l & 15;
  const int m0 = blockIdx.y * 128, n0 = blockIdx.x * 128;
  const int wr = w >> 1, wc = w & 1;

  floatx4 acc[4][4] = {};

  for (int k0 = 0; k0 < K; k0 += 32) {
    __syncthreads();
#pragma unroll
    for (int p = 0; p < 2; ++p) {
      const int c0 = (p * 4 + w) * 64;
      const int c = c0 + l;
      const int row = c >> 2;
      const int koff = (c & 3) * 8;
      gll16(A + (size_t)(m0 + row) * K + k0 + koff, &As[c0 * 8]);
      gll16(Bt + (size_t)(n0 + row) * K + k0 + koff, &Bs[c0 * 8]);
    }
    __syncthreads();

    short8 af[4], bf[4];
#pragma unroll
    for (int i = 0; i < 4; ++i)
      af[i] = *(const short8*)&As[(wr * 64 + i * 16 + l16) * 32 + quad * 8];
#pragma unroll
    for (int j = 0; j < 4; ++j)
      bf[j] = *(const short8*)&Bs[(wc * 64 + j * 16 + l16) * 32 + quad * 8];
#pragma unroll
    for (int i = 0; i < 4; ++i)
#pragma unroll
      for (int j = 0; j < 4; ++j)
        acc[i][j] = __builtin_amdgcn_mfma_f32_16x16x32_bf16(af[i], bf[j], acc[i][j], 0, 0, 0);
  }

  const int seg = n0 >> 10;  // 0=Q 1=K 2=V (128 | 1024 so block is seg-pure)
  const float* bias = (seg == 0) ? bq : (seg == 1) ? bk : bv;
#pragma unroll
  for (int j = 0; j < 4; ++j) {
    const int nn = (n0 & 1023) + wc * 64 + j * 16 + l16;
    const float bvs = bias[nn];
    const int h = nn >> 6, dh = nn & 63;
#pragma unroll
    for (int i = 0; i < 4; ++i) {
      const int rb = m0 + wr * 64 + i * 16 + quad * 4;
#pragma unroll
      for (int r = 0; r < 4; ++r) {
        const int m = rb + r;
        const float v = acc[i][j][r] + bvs;
        const int b = m >> 11, ll = m & 2047;
        if (seg < 2) {
          u16* dst = seg ? Kb : Qb;
          dst[((size_t)(b * 16 + h) * 2048 + ll) * 64 + dh] = f2bf(v);
        } else {
          Vtb[((size_t)(b * 16 + h) * 64 + dh) * 2048 + ll] = f2bf(v);
        }
      }
    }
  }
}

// ---------------------------------------------------------------------------
// Out GEMM: C[M,N] f32 = A[M,K] bf16 @ Bt[N,K]^T + bias[N].
__global__ __launch_bounds__(256, 2) void gemm_out(
    const u16* __restrict__ A, const u16* __restrict__ Bt,
    const float* __restrict__ bias, float* __restrict__ C, int M, int N, int K) {
  __shared__ __align__(16) u16 As[128 * 32];
  __shared__ __align__(16) u16 Bs[128 * 32];
  const int t = threadIdx.x;
  const int w = t >> 6, l = t & 63;
  const int quad = l >> 4, l16 = l & 15;
  const int m0 = blockIdx.y * 128, n0 = blockIdx.x * 128;
  const int wr = w >> 1, wc = w & 1;

  floatx4 acc[4][4] = {};

  for (int k0 = 0; k0 < K; k0 += 32) {
    __syncthreads();
#pragma unroll
    for (int p = 0; p < 2; ++p) {
      const int c0 = (p * 4 + w) * 64;
      const int c = c0 + l;
      const int row = c >> 2;
      const int koff = (c & 3) * 8;
      gll16(A + (size_t)(m0 + row) * K + k0 + koff, &As[c0 * 8]);
      gll16(Bt + (size_t)(n0 + row) * K + k0 + koff, &Bs[c0 * 8]);
    }
    __syncthreads();

    short8 af[4], bf[4];
#pragma unroll
    for (int i = 0; i < 4; ++i)
      af[i] = *(const short8*)&As[(wr * 64 + i * 16 + l16) * 32 + quad * 8];
#pragma unroll
    for (int j = 0; j < 4; ++j)
      bf[j] = *(const short8*)&Bs[(wc * 64 + j * 16 + l16) * 32 + quad * 8];
#pragma unroll
    for (int i = 0; i < 4; ++i)
#pragma unroll
      for (int j = 0; j < 4; ++j)
        acc[i][j] = __builtin_amdgcn_mfma_f32_16x16x32_bf16(af[i], bf[j], acc[i][j], 0, 0, 0);
  }

#pragma unroll
  for (int j = 0; j < 4; ++j) {
    const int n = n0 + wc * 64 + j * 16 + l16;
    const float bvs = bias[n];
#pragma unroll
    for (int i = 0; i < 4; ++i) {
      const int rb = m0 + wr * 64 + i * 16 + quad * 4;
#pragma unroll
      for (int r = 0; r < 4; ++r)
        C[(size_t)(rb + r) * N + n] = acc[i][j][r] + bvs;
    }
  }
}

// ---------------------------------------------------------------------------
// Flash attention, causal. Block = (b*16+h, 64-row q-tile); wave owns 16 rows,
// Q in registers. Register-prefetch K/V pipeline: tile kt+1 global loads are
// in flight during compute of tile kt. LDS stride 68 (verified 0 conflicts, R5).
#define ATT_STRIDE 68
__global__ __launch_bounds__(256, 6) void attn_kernel(
    const u16* __restrict__ Q, const u16* __restrict__ K,
    const u16* __restrict__ Vt, u16* __restrict__ ctx) {
  __shared__ __align__(16) u16 Ks[64 * ATT_STRIDE];
  __shared__ __align__(16) u16 Vs[64 * ATT_STRIDE];          // V^T tile [d][k]
  __shared__ __align__(16) u16 Ps[4 * 16 * ATT_STRIDE];      // per-wave P hop

  const int t = threadIdx.x;
  const int w = t >> 6, l = t & 63;
  const int quad = l >> 4, l16 = l & 15;
  const int qt = gridDim.x - 1 - blockIdx.x;  // heavy tiles first
  const int bh = blockIdx.y;
  const int q0 = qt * 64;
  const size_t qkbase = (size_t)bh * (2048 * 64);
  u16* Pw = &Ps[w * 16 * ATT_STRIDE];

  // Q fragments in registers (A-layout): row = q0+w*16+l16, k = ks*32+quad*8
  short8 aq[2];
#pragma unroll
  for (int ks = 0; ks < 2; ++ks)
    aq[ks] = *(const short8*)(Q + qkbase +
        (size_t)(q0 + w * 16 + l16) * 64 + ks * 32 + quad * 8);

  // prefetch tile kt=0 into registers (2 chunks each for K and V per thread)
  const int prow0 = t >> 3, prow1 = 32 + (t >> 3), pcc = (t & 7) * 8;
  short8 kreg[2], vreg[2];
  kreg[0] = *(const short8*)(K + qkbase + (size_t)prow0 * 64 + pcc);
  kreg[1] = *(const short8*)(K + qkbase + (size_t)prow1 * 64 + pcc);
  vreg[0] = *(const short8*)(Vt + qkbase + (size_t)prow0 * 2048 + pcc);
  vreg[1] = *(const short8*)(Vt + qkbase + (size_t)prow1 * 2048 + pcc);

  floatx4 o[4] = {};
  float mrow[4], lrow[4];
#pragma unroll
  for (int r = 0; r < 4; ++r) { mrow[r] = NEG_BIG; lrow[r] = 0.f; }

  for (int kt = 0; kt <= qt; ++kt) {
    __syncthreads();  // all waves done reading Ks/Vs of prev iter
    // publish prefetched tile (implicit vmcnt wait on kreg/vreg)
    *(short8*)&Ks[prow0 * ATT_STRIDE + pcc] = kreg[0];
    *(short8*)&Ks[prow1 * ATT_STRIDE + pcc] = kreg[1];
    *(short8*)&Vs[prow0 * ATT_STRIDE + pcc] = vreg[0];
    *(short8*)&Vs[prow1 * ATT_STRIDE + pcc] = vreg[1];
    // issue next tile's loads — in flight during this iter's compute
    if (kt < qt) {
      const int kn = (kt + 1) * 64;
      kreg[0] = *(const short8*)(K + qkbase + (size_t)(kn + prow0) * 64 + pcc);
      kreg[1] = *(const short8*)(K + qkbase + (size_t)(kn + prow1) * 64 + pcc);
      vreg[0] = *(const short8*)(Vt + qkbase + (size_t)prow0 * 2048 + kn + pcc);
      vreg[1] = *(const short8*)(Vt + qkbase + (size_t)prow1 * 2048 + kn + pcc);
    }
    __syncthreads();  // staged K/V visible to all waves

    // S = Q K^T : 8 MFMA. Wave rows q0+w*16+(quad*4+r), cols kt*64+tn*16+l16
    floatx4 s[4] = {};
#pragma unroll
    for (int ks = 0; ks < 2; ++ks)
#pragma unroll
      for (int tn = 0; tn < 4; ++tn) {
        const short8 bk = *(const short8*)&Ks[(tn * 16 + l16) * ATT_STRIDE + ks * 32 + quad * 8];
        s[tn] = __builtin_amdgcn_mfma_f32_16x16x32_bf16(aq[ks], bk, s[tn], 0, 0, 0);
      }

    // scale + causal mask (only diagonal tile has masked entries)
    const bool diag = (kt == qt);
#pragma unroll
    for (int tn = 0; tn < 4; ++tn)
#pragma unroll
      for (int r = 0; r < 4; ++r) {
        float v = s[tn][r] * 0.125f;  // 1/sqrt(64)
        if (diag && (tn * 16 + l16 > w * 16 + quad * 4 + r)) v = NEG_BIG;
        s[tn][r] = v;
      }

    // online softmax (row's 64 cols live across one quad's 16 lanes)
    float alpha[4];
#pragma unroll
    for (int r = 0; r < 4; ++r) {
      float mx = fmaxf(fmaxf(s[0][r], s[1][r]), fmaxf(s[2][r], s[3][r]));
#pragma unroll
      for (int off = 8; off >= 1; off >>= 1)
        mx = fmaxf(mx, __shfl_xor(mx, off, 16));
      const float mnew = fmaxf(mrow[r], mx);
      alpha[r] = __expf(mrow[r] - mnew);
      mrow[r] = mnew;
      float rs = 0.f;
#pragma unroll
      for (int tn = 0; tn < 4; ++tn) {
        const float p = __expf(s[tn][r] - mnew);
        s[tn][r] = p;
        rs += p;
      }
#pragma unroll
      for (int off = 8; off >= 1; off >>= 1)
        rs += __shfl_xor(rs, off, 16);
      lrow[r] = lrow[r] * alpha[r] + rs;
    }
#pragma unroll
    for (int td = 0; td < 4; ++td)
#pragma unroll
      for (int r = 0; r < 4; ++r) o[td][r] *= alpha[r];

    // P: C-layout -> wave-private LDS -> A-layout (wave-level sync only)
#pragma unroll
    for (int tn = 0; tn < 4; ++tn)
#pragma unroll
      for (int r = 0; r < 4; ++r)
        Pw[(quad * 4 + r) * ATT_STRIDE + tn * 16 + l16] = f2bf(s[tn][r]);
    __asm__ volatile("s_waitcnt lgkmcnt(0)" ::: "memory");
    __builtin_amdgcn_wave_barrier();

    // O += P V : 8 MFMA
#pragma unroll
    for (int ks = 0; ks < 2; ++ks) {
      const short8 ap = *(const short8*)&Pw[l16 * ATT_STRIDE + ks * 32 + quad * 8];
#pragma unroll
      for (int td = 0; td < 4; ++td) {
        const short8 bv = *(const short8*)&Vs[(td * 16 + l16) * ATT_STRIDE + ks * 32 + quad * 8];
        o[td] = __builtin_amdgcn_mfma_f32_16x16x32_bf16(ap, bv, o[td], 0, 0, 0);
      }
    }
  }

  // normalize + store ctx[b, l, h*64+dh] (bf16)
  const int b = bh >> 4, h = bh & 15;
#pragma unroll
  for (int r = 0; r < 4; ++r) {
    const float inv = 1.f / lrow[r];
    const int gq = q0 + w * 16 + quad * 4 + r;
    const size_t rowbase = ((size_t)(b * 2048 + gq)) * 1024 + h * 64;
#pragma unroll
    for (int td = 0; td < 4; ++td)
      ctx[rowbase + td * 16 + l16] = f2bf(o[td][r] * inv);
  }
}

// ---------------------------------------------------------------------------
extern "C" void kernel_launch(void* const* d_in, const int* in_sizes, int n_in,
                              void* d_out, int out_size, void* d_ws, size_t ws_size,
                              hipStream_t stream) {
  const float* x  = (const float*)d_in[0];
  // d_in[1] = attn_mask (causal tril) — implemented analytically
  const float* Wq = (const float*)d_in[2];
  const float* bq = (const float*)d_in[3];
  const float* Wk = (const float*)d_in[4];
  const float* bk = (const float*)d_in[5];
  const float* Wv = (const float*)d_in[6];
  const float* bv = (const float*)d_in[7];
  const float* Wo = (const float*)d_in[8];
  const float* bo = (const float*)d_in[9];

  u16* ws = (u16*)d_ws;
  const size_t WSZ = 1u << 20;   // 1024*1024
  const size_t TSZ = 8u << 20;   // 8192*1024
  u16* WqT = ws;                 // WqT|WkT|WvT contiguous = 3072x1024 Bt
  u16* WkT = ws + WSZ;
  u16* WvT = ws + 2 * WSZ;
  u16* WoT = ws + 3 * WSZ;
  u16* xb  = ws + 4 * WSZ;       // x as bf16; reused as Ctx after attention
  u16* Qb  = xb + TSZ;
  u16* Kb  = Qb + TSZ;
  u16* Vtb = Kb + TSZ;
  u16* Ctx = xb;

  const dim3 tb(256);
  cvt_x<<<dim3(4096), tb, 0, stream>>>(x, xb);
  transpose4<<<dim3(16, 16, 4), tb, 0, stream>>>(Wq, Wk, Wv, Wo, WqT, WkT, WvT, WoT);
  gemm_qkv<<<dim3(24, 64), tb, 0, stream>>>(xb, WqT, bq, bk, bv, Qb, Kb, Vtb);
  attn_kernel<<<dim3(32, 64), tb, 0, stream>>>(Qb, Kb, Vtb, Ctx);
  gemm_out<<<dim3(8, 64), tb, 0, stream>>>(Ctx, WoT, bo, (float*)d_out, 8192, 1024, 1024);
}

// Round 7
// 486.552 us; speedup vs baseline: 1.1128x; 1.1128x over previous
//
#include <hip/hip_runtime.h>

// MHA forward. f32 in/out; bf16 MFMA compute (16x16x32), fp32 accum.
// Pipeline: cvt_x + transposeW -> merged QKV GEMM -> flash attention
//           (64-row q-tiles, Q in regs, reg-prefetch K/V pipeline) -> out GEMM.
// Workspace (u16): WqT,WkT,WvT (contig, = 3072x1024 Bt), WoT, xb/Ctx (alias),
// Q, K, Vt = 72 MB.
//
// R7 vs R6: ONE change — attn __launch_bounds__(256,6) -> (256,4). R6's bound-6
// forced VGPR to 40 and spilled the prefetch registers to scratch (WRITE_SIZE
// 205 MB = spill traffic). Bound-4 gives a 128-VGPR budget; state (~90) fits.

typedef unsigned short u16;
typedef __attribute__((ext_vector_type(8))) short short8;   // 8 bf16
typedef __attribute__((ext_vector_type(4))) float floatx4;  // 4 fp32

#define NEG_BIG (-1e30f)

__device__ __forceinline__ u16 f2bf(float f) {
  unsigned int u = __builtin_bit_cast(unsigned int, f);
  u += 0x7fffu + ((u >> 16) & 1u);
  return (u16)(u >> 16);
}

__device__ __forceinline__ short8 cvt8(const float* __restrict__ p) {
  const floatx4 a = *(const floatx4*)p;
  const floatx4 b = *(const floatx4*)(p + 4);
  short8 r;
  r[0] = (short)f2bf(a[0]); r[1] = (short)f2bf(a[1]);
  r[2] = (short)f2bf(a[2]); r[3] = (short)f2bf(a[3]);
  r[4] = (short)f2bf(b[0]); r[5] = (short)f2bf(b[1]);
  r[6] = (short)f2bf(b[2]); r[7] = (short)f2bf(b[3]);
  return r;
}

// async global->LDS, 16B/lane; LDS dest = wave-uniform base + lane*16 [m97]
__device__ __forceinline__ void gll16(const u16* g, u16* l) {
  __builtin_amdgcn_global_load_lds((const __attribute__((address_space(1))) void*)g,
                                   (__attribute__((address_space(3))) void*)l,
                                   16, 0, 0);
}

// ---------------------------------------------------------------------------
__global__ void cvt_x(const float* __restrict__ x, u16* __restrict__ xb) {
  const int i = blockIdx.x * 256 + threadIdx.x;  // 8 elems each
  *(short8*)(xb + (size_t)i * 8) = cvt8(x + (size_t)i * 8);
}

// ---------------------------------------------------------------------------
// 1024x1024 transpose + f32->bf16 (x4 matrices via grid.z).
__global__ void transpose4(const float* __restrict__ s0, const float* __restrict__ s1,
                           const float* __restrict__ s2, const float* __restrict__ s3,
                           u16* __restrict__ d0, u16* __restrict__ d1,
                           u16* __restrict__ d2, u16* __restrict__ d3) {
  __shared__ u16 tile[64][72];
  const float* src; u16* dst;
  switch (blockIdx.z) {
    case 0: src = s0; dst = d0; break;
    case 1: src = s1; dst = d1; break;
    case 2: src = s2; dst = d2; break;
    default: src = s3; dst = d3; break;
  }
  const int t = threadIdx.x;
  const int c = t & 63, rg = t >> 6;
  const int x0 = blockIdx.x * 64, y0 = blockIdx.y * 64;
#pragma unroll
  for (int i = 0; i < 16; ++i) {
    const int row = rg * 16 + i;
    tile[row][c] = f2bf(src[(size_t)(y0 + row) * 1024 + x0 + c]);
  }
  __syncthreads();
#pragma unroll
  for (int i = 0; i < 16; ++i) {
    const int row = rg * 16 + i;
    dst[(size_t)(x0 + row) * 1024 + y0 + c] = tile[c][row];
  }
}

// ---------------------------------------------------------------------------
// Merged QKV GEMM: A[8192,1024] bf16 @ Bt[3072,1024]^T (WqT|WkT|WvT) + bias.
// 128x128 tile, BK=32, m97 gll staging. Epilogue routes by segment:
// seg0 -> Qb [b,h,l,dh], seg1 -> Kb [b,h,l,dh], seg2 -> Vtb [b,h,dh,l].
__global__ __launch_bounds__(256, 2) void gemm_qkv(
    const u16* __restrict__ A, const u16* __restrict__ Bt,
    const float* __restrict__ bq, const float* __restrict__ bk,
    const float* __restrict__ bv,
    u16* __restrict__ Qb, u16* __restrict__ Kb, u16* __restrict__ Vtb) {
  const int K = 1024;
  __shared__ __align__(16) u16 As[128 * 32];
  __shared__ __align__(16) u16 Bs[128 * 32];
  const int t = threadIdx.x;
  const int w = t >> 6, l = t & 63;
  const int quad = l >> 4, l16 = l & 15;
  const int m0 = blockIdx.y * 128, n0 = blockIdx.x * 128;
  const int wr = w >> 1, wc = w & 1;

  floatx4 acc[4][4] = {};

  for (int k0 = 0; k0 < K; k0 += 32) {
    __syncthreads();
#pragma unroll
    for (int p = 0; p < 2; ++p) {
      const int c0 = (p * 4 + w) * 64;
      const int c = c0 + l;
      const int row = c >> 2;
      const int koff = (c & 3) * 8;
      gll16(A + (size_t)(m0 + row) * K + k0 + koff, &As[c0 * 8]);
      gll16(Bt + (size_t)(n0 + row) * K + k0 + koff, &Bs[c0 * 8]);
    }
    __syncthreads();

    short8 af[4], bf[4];
#pragma unroll
    for (int i = 0; i < 4; ++i)
      af[i] = *(const short8*)&As[(wr * 64 + i * 16 + l16) * 32 + quad * 8];
#pragma unroll
    for (int j = 0; j < 4; ++j)
      bf[j] = *(const short8*)&Bs[(wc * 64 + j * 16 + l16) * 32 + quad * 8];
#pragma unroll
    for (int i = 0; i < 4; ++i)
#pragma unroll
      for (int j = 0; j < 4; ++j)
        acc[i][j] = __builtin_amdgcn_mfma_f32_16x16x32_bf16(af[i], bf[j], acc[i][j], 0, 0, 0);
  }

  const int seg = n0 >> 10;  // 0=Q 1=K 2=V (128 | 1024 so block is seg-pure)
  const float* bias = (seg == 0) ? bq : (seg == 1) ? bk : bv;
#pragma unroll
  for (int j = 0; j < 4; ++j) {
    const int nn = (n0 & 1023) + wc * 64 + j * 16 + l16;
    const float bvs = bias[nn];
    const int h = nn >> 6, dh = nn & 63;
#pragma unroll
    for (int i = 0; i < 4; ++i) {
      const int rb = m0 + wr * 64 + i * 16 + quad * 4;
#pragma unroll
      for (int r = 0; r < 4; ++r) {
        const int m = rb + r;
        const float v = acc[i][j][r] + bvs;
        const int b = m >> 11, ll = m & 2047;
        if (seg < 2) {
          u16* dst = seg ? Kb : Qb;
          dst[((size_t)(b * 16 + h) * 2048 + ll) * 64 + dh] = f2bf(v);
        } else {
          Vtb[((size_t)(b * 16 + h) * 64 + dh) * 2048 + ll] = f2bf(v);
        }
      }
    }
  }
}

// ---------------------------------------------------------------------------
// Out GEMM: C[M,N] f32 = A[M,K] bf16 @ Bt[N,K]^T + bias[N].
__global__ __launch_bounds__(256, 2) void gemm_out(
    const u16* __restrict__ A, const u16* __restrict__ Bt,
    const float* __restrict__ bias, float* __restrict__ C, int M, int N, int K) {
  __shared__ __align__(16) u16 As[128 * 32];
  __shared__ __align__(16) u16 Bs[128 * 32];
  const int t = threadIdx.x;
  const int w = t >> 6, l = t & 63;
  const int quad = l >> 4, l16 = l & 15;
  const int m0 = blockIdx.y * 128, n0 = blockIdx.x * 128;
  const int wr = w >> 1, wc = w & 1;

  floatx4 acc[4][4] = {};

  for (int k0 = 0; k0 < K; k0 += 32) {
    __syncthreads();
#pragma unroll
    for (int p = 0; p < 2; ++p) {
      const int c0 = (p * 4 + w) * 64;
      const int c = c0 + l;
      const int row = c >> 2;
      const int koff = (c & 3) * 8;
      gll16(A + (size_t)(m0 + row) * K + k0 + koff, &As[c0 * 8]);
      gll16(Bt + (size_t)(n0 + row) * K + k0 + koff, &Bs[c0 * 8]);
    }
    __syncthreads();

    short8 af[4], bf[4];
#pragma unroll
    for (int i = 0; i < 4; ++i)
      af[i] = *(const short8*)&As[(wr * 64 + i * 16 + l16) * 32 + quad * 8];
#pragma unroll
    for (int j = 0; j < 4; ++j)
      bf[j] = *(const short8*)&Bs[(wc * 64 + j * 16 + l16) * 32 + quad * 8];
#pragma unroll
    for (int i = 0; i < 4; ++i)
#pragma unroll
      for (int j = 0; j < 4; ++j)
        acc[i][j] = __builtin_amdgcn_mfma_f32_16x16x32_bf16(af[i], bf[j], acc[i][j], 0, 0, 0);
  }

#pragma unroll
  for (int j = 0; j < 4; ++j) {
    const int n = n0 + wc * 64 + j * 16 + l16;
    const float bvs = bias[n];
#pragma unroll
    for (int i = 0; i < 4; ++i) {
      const int rb = m0 + wr * 64 + i * 16 + quad * 4;
#pragma unroll
      for (int r = 0; r < 4; ++r)
        C[(size_t)(rb + r) * N + n] = acc[i][j][r] + bvs;
    }
  }
}

// ---------------------------------------------------------------------------
// Flash attention, causal. Block = (b*16+h, 64-row q-tile); wave owns 16 rows,
// Q in registers. Register-prefetch K/V pipeline: tile kt+1 global loads are
// in flight during compute of tile kt. LDS stride 68 (verified 0 conflicts, R5).
#define ATT_STRIDE 68
__global__ __launch_bounds__(256, 4) void attn_kernel(
    const u16* __restrict__ Q, const u16* __restrict__ K,
    const u16* __restrict__ Vt, u16* __restrict__ ctx) {
  __shared__ __align__(16) u16 Ks[64 * ATT_STRIDE];
  __shared__ __align__(16) u16 Vs[64 * ATT_STRIDE];          // V^T tile [d][k]
  __shared__ __align__(16) u16 Ps[4 * 16 * ATT_STRIDE];      // per-wave P hop

  const int t = threadIdx.x;
  const int w = t >> 6, l = t & 63;
  const int quad = l >> 4, l16 = l & 15;
  const int qt = gridDim.x - 1 - blockIdx.x;  // heavy tiles first
  const int bh = blockIdx.y;
  const int q0 = qt * 64;
  const size_t qkbase = (size_t)bh * (2048 * 64);
  u16* Pw = &Ps[w * 16 * ATT_STRIDE];

  // Q fragments in registers (A-layout): row = q0+w*16+l16, k = ks*32+quad*8
  short8 aq[2];
#pragma unroll
  for (int ks = 0; ks < 2; ++ks)
    aq[ks] = *(const short8*)(Q + qkbase +
        (size_t)(q0 + w * 16 + l16) * 64 + ks * 32 + quad * 8);

  // prefetch tile kt=0 into registers (2 chunks each for K and V per thread)
  const int prow0 = t >> 3, prow1 = 32 + (t >> 3), pcc = (t & 7) * 8;
  short8 kreg[2], vreg[2];
  kreg[0] = *(const short8*)(K + qkbase + (size_t)prow0 * 64 + pcc);
  kreg[1] = *(const short8*)(K + qkbase + (size_t)prow1 * 64 + pcc);
  vreg[0] = *(const short8*)(Vt + qkbase + (size_t)prow0 * 2048 + pcc);
  vreg[1] = *(const short8*)(Vt + qkbase + (size_t)prow1 * 2048 + pcc);

  floatx4 o[4] = {};
  float mrow[4], lrow[4];
#pragma unroll
  for (int r = 0; r < 4; ++r) { mrow[r] = NEG_BIG; lrow[r] = 0.f; }

  for (int kt = 0; kt <= qt; ++kt) {
    __syncthreads();  // all waves done reading Ks/Vs of prev iter
    // publish prefetched tile (implicit vmcnt wait on kreg/vreg)
    *(short8*)&Ks[prow0 * ATT_STRIDE + pcc] = kreg[0];
    *(short8*)&Ks[prow1 * ATT_STRIDE + pcc] = kreg[1];
    *(short8*)&Vs[prow0 * ATT_STRIDE + pcc] = vreg[0];
    *(short8*)&Vs[prow1 * ATT_STRIDE + pcc] = vreg[1];
    // issue next tile's loads — in flight during this iter's compute
    if (kt < qt) {
      const int kn = (kt + 1) * 64;
      kreg[0] = *(const short8*)(K + qkbase + (size_t)(kn + prow0) * 64 + pcc);
      kreg[1] = *(const short8*)(K + qkbase + (size_t)(kn + prow1) * 64 + pcc);
      vreg[0] = *(const short8*)(Vt + qkbase + (size_t)prow0 * 2048 + kn + pcc);
      vreg[1] = *(const short8*)(Vt + qkbase + (size_t)prow1 * 2048 + kn + pcc);
    }
    __syncthreads();  // staged K/V visible to all waves

    // S = Q K^T : 8 MFMA. Wave rows q0+w*16+(quad*4+r), cols kt*64+tn*16+l16
    floatx4 s[4] = {};
#pragma unroll
    for (int ks = 0; ks < 2; ++ks)
#pragma unroll
      for (int tn = 0; tn < 4; ++tn) {
        const short8 bk = *(const short8*)&Ks[(tn * 16 + l16) * ATT_STRIDE + ks * 32 + quad * 8];
        s[tn] = __builtin_amdgcn_mfma_f32_16x16x32_bf16(aq[ks], bk, s[tn], 0, 0, 0);
      }

    // scale + causal mask (only diagonal tile has masked entries)
    const bool diag = (kt == qt);
#pragma unroll
    for (int tn = 0; tn < 4; ++tn)
#pragma unroll
      for (int r = 0; r < 4; ++r) {
        float v = s[tn][r] * 0.125f;  // 1/sqrt(64)
        if (diag && (tn * 16 + l16 > w * 16 + quad * 4 + r)) v = NEG_BIG;
        s[tn][r] = v;
      }

    // online softmax (row's 64 cols live across one quad's 16 lanes)
    float alpha[4];
#pragma unroll
    for (int r = 0; r < 4; ++r) {
      float mx = fmaxf(fmaxf(s[0][r], s[1][r]), fmaxf(s[2][r], s[3][r]));
#pragma unroll
      for (int off = 8; off >= 1; off >>= 1)
        mx = fmaxf(mx, __shfl_xor(mx, off, 16));
      const float mnew = fmaxf(mrow[r], mx);
      alpha[r] = __expf(mrow[r] - mnew);
      mrow[r] = mnew;
      float rs = 0.f;
#pragma unroll
      for (int tn = 0; tn < 4; ++tn) {
        const float p = __expf(s[tn][r] - mnew);
        s[tn][r] = p;
        rs += p;
      }
#pragma unroll
      for (int off = 8; off >= 1; off >>= 1)
        rs += __shfl_xor(rs, off, 16);
      lrow[r] = lrow[r] * alpha[r] + rs;
    }
#pragma unroll
    for (int td = 0; td < 4; ++td)
#pragma unroll
      for (int r = 0; r < 4; ++r) o[td][r] *= alpha[r];

    // P: C-layout -> wave-private LDS -> A-layout (wave-level sync only)
#pragma unroll
    for (int tn = 0; tn < 4; ++tn)
#pragma unroll
      for (int r = 0; r < 4; ++r)
        Pw[(quad * 4 + r) * ATT_STRIDE + tn * 16 + l16] = f2bf(s[tn][r]);
    __asm__ volatile("s_waitcnt lgkmcnt(0)" ::: "memory");
    __builtin_amdgcn_wave_barrier();

    // O += P V : 8 MFMA
#pragma unroll
    for (int ks = 0; ks < 2; ++ks) {
      const short8 ap = *(const short8*)&Pw[l16 * ATT_STRIDE + ks * 32 + quad * 8];
#pragma unroll
      for (int td = 0; td < 4; ++td) {
        const short8 bv = *(const short8*)&Vs[(td * 16 + l16) * ATT_STRIDE + ks * 32 + quad * 8];
        o[td] = __builtin_amdgcn_mfma_f32_16x16x32_bf16(ap, bv, o[td], 0, 0, 0);
      }
    }
  }

  // normalize + store ctx[b, l, h*64+dh] (bf16)
  const int b = bh >> 4, h = bh & 15;
#pragma unroll
  for (int r = 0; r < 4; ++r) {
    const float inv = 1.f / lrow[r];
    const int gq = q0 + w * 16 + quad * 4 + r;
    const size_t rowbase = ((size_t)(b * 2048 + gq)) * 1024 + h * 64;
#pragma unroll
    for (int td = 0; td < 4; ++td)
      ctx[rowbase + td * 16 + l16] = f2bf(o[td][r] * inv);
  }
}

// ---------------------------------------------------------------------------
extern "C" void kernel_launch(void* const* d_in, const int* in_sizes, int n_in,
                              void* d_out, int out_size, void* d_ws, size_t ws_size,
                              hipStream_t stream) {
  const float* x  = (const float*)d_in[0];
  // d_in[1] = attn_mask (causal tril) — implemented analytically
  const float* Wq = (const float*)d_in[2];
  const float* bq = (const float*)d_in[3];
  const float* Wk = (const float*)d_in[4];
  const float* bk = (const float*)d_in[5];
  const float* Wv = (const float*)d_in[6];
  const float* bv = (const float*)d_in[7];
  const float* Wo = (const float*)d_in[8];
  const float* bo = (const float*)d_in[9];

  u16* ws = (u16*)d_ws;
  const size_t WSZ = 1u << 20;   // 1024*1024
  const size_t TSZ = 8u << 20;   // 8192*1024
  u16* WqT = ws;                 // WqT|WkT|WvT contiguous = 3072x1024 Bt
  u16* WkT = ws + WSZ;
  u16* WvT = ws + 2 * WSZ;
  u16* WoT = ws + 3 * WSZ;
  u16* xb  = ws + 4 * WSZ;       // x as bf16; reused as Ctx after attention
  u16* Qb  = xb + TSZ;
  u16* Kb  = Qb + TSZ;
  u16* Vtb = Kb + TSZ;
  u16* Ctx = xb;

  const dim3 tb(256);
  cvt_x<<<dim3(4096), tb, 0, stream>>>(x, xb);
  transpose4<<<dim3(16, 16, 4), tb, 0, stream>>>(Wq, Wk, Wv, Wo, WqT, WkT, WvT, WoT);
  gemm_qkv<<<dim3(24, 64), tb, 0, stream>>>(xb, WqT, bq, bk, bv, Qb, Kb, Vtb);
  attn_kernel<<<dim3(32, 64), tb, 0, stream>>>(Qb, Kb, Vtb, Ctx);
  gemm_out<<<dim3(8, 64), tb, 0, stream>>>(Ctx, WoT, bo, (float*)d_out, 8192, 1024, 1024);
}